// Round 5
// baseline (1247.737 us; speedup 1.0000x reference)
//
#include <hip/hip_runtime.h>
#include <math.h>

// Problem constants (B,T,D,H,L from the reference)
#define BB 4
#define TT 2048
#define DD 512
#define HH 8
#define EPS 1e-5f
#define SCALE 0.125f            // dh^-0.5, dh=64
#define LOCALN 128              // blocks per batch
#define NBLK 512                // total blocks (2 per CU guaranteed by LDS)

struct Params {
  const float *x_vid, *x_aud;
  const int *vid_kpm, *aud_kpm;
  const float *Wq_v, *Wk_av, *Wq_a, *Wk_va;   // (L,D,D) each
  const float *vg_W1, *vg_b1, *vg_W2, *vg_b2;
  const float *ag_W1, *ag_b1, *ag_W2, *ag_b2;
  const float *vid_g, *vid_b, *aud_g, *aud_b; // (L,D)
  float *xv, *xa;                              // outputs
  float *partial, *nsum, *mg, *fs;             // scratch
  unsigned *bar;                               // 48 barrier counters (zeroed per launch)
};

__device__ __forceinline__ float wred(float s) {
#pragma unroll
  for (int off = 32; off > 0; off >>= 1) s += __shfl_xor(s, off);
  return s;
}

__device__ __forceinline__ void ldf(const float* p, int lane, float f[8]) {
  float4 a = *reinterpret_cast<const float4*>(p + lane * 4);
  float4 c = *reinterpret_cast<const float4*>(p + 256 + lane * 4);
  f[0]=a.x; f[1]=a.y; f[2]=a.z; f[3]=a.w;
  f[4]=c.x; f[5]=c.y; f[6]=c.z; f[7]=c.w;
}

// per-batch barrier: release-add, relaxed spin, acquire after
__device__ __forceinline__ void bbar(unsigned* c) {
  __syncthreads();
  if (threadIdx.x == 0) {
    __threadfence();
    __hip_atomic_fetch_add(c, 1u, __ATOMIC_RELEASE, __HIP_MEMORY_SCOPE_AGENT);
    while (__hip_atomic_load(c, __ATOMIC_RELAXED, __HIP_MEMORY_SCOPE_AGENT) < (unsigned)LOCALN)
      __builtin_amdgcn_s_sleep(1);
  }
  __syncthreads();
  __threadfence();
}

// combine 4 waves' 512-float accumulators -> wave 0 stores to dst (global)
__device__ __forceinline__ void emit_store(float e[8], int wave, int lane,
                                           float (*sc2)[DD], float* dst) {
  __syncthreads();
  if (wave & 1) {                   // waves 1,3 write slots 0,1
    const int s = wave >> 1;
#pragma unroll
    for (int k = 0; k < 4; ++k) { sc2[s][lane*4+k] = e[k]; sc2[s][256+lane*4+k] = e[4+k]; }
  }
  __syncthreads();
  if (!(wave & 1)) {                // waves 0,2 add their pair
    const int s = wave >> 1;
#pragma unroll
    for (int k = 0; k < 4; ++k) { e[k] += sc2[s][lane*4+k]; e[4+k] += sc2[s][256+lane*4+k]; }
  }
  if (wave == 2) {                  // wave 2 republishes combined (2+3)
#pragma unroll
    for (int k = 0; k < 4; ++k) { sc2[1][lane*4+k] = e[k]; sc2[1][256+lane*4+k] = e[4+k]; }
  }
  __syncthreads();
  if (wave == 0) {
#pragma unroll
    for (int k = 0; k < 4; ++k) { e[k] += sc2[1][lane*4+k]; e[4+k] += sc2[1][256+lane*4+k]; }
    *reinterpret_cast<float4*>(dst + lane*4)       = make_float4(e[0],e[1],e[2],e[3]);
    *reinterpret_cast<float4*>(dst + 256 + lane*4) = make_float4(e[4],e[5],e[6],e[7]);
  }
}

__global__ __launch_bounds__(256, 2) void fused_all(Params P) {
  const int blk   = blockIdx.x;
  const int b     = blk >> 7;
  const int local = blk & (LOCALN - 1);
  const int tid   = threadIdx.x;
  const int wave  = tid >> 6;
  const int lane  = tid & 63;
  const int rowbase = b * TT + local * 16;

  __shared__ __align__(16) float rows[32][DD];   // 0..15 vid, 16..31 aud (64 KB)
  __shared__ __align__(16) float sc2[2][DD];     // 4 KB scratch
  __shared__ float mean_s[32], var_s[32];
  __shared__ int kvm[16], kam[16];
  __shared__ float mlp[164];
  __shared__ float ksl[64];
  __shared__ float csh[4];

  // ================= stage 0: load rows, stats, counts, emit p0 keys =======
  if (tid < 16) kvm[tid] = P.vid_kpm[rowbase + tid];
  else if (tid < 32) kam[tid - 16] = P.aud_kpm[rowbase + tid - 16];

  float g0[8], b0[8];
  ldf(P.vid_g, lane, g0);     // vid_ln[0] — key-side LN for phase 0
  ldf(P.vid_b, lane, b0);

  float eacc[8] = {0.f,0.f,0.f,0.f,0.f,0.f,0.f,0.f};

  for (int j = 0; j < 8; ++j) {
    const int rl   = wave * 4 + (j & 3);
    const int ridx = (j < 4) ? rl : 16 + rl;
    const float* src = ((j < 4) ? P.x_vid : P.x_aud) + (size_t)(rowbase + rl) * DD;
    float v[8];
    ldf(src, lane, v);
    *reinterpret_cast<float4*>(&rows[ridx][lane*4])     = make_float4(v[0],v[1],v[2],v[3]);
    *reinterpret_cast<float4*>(&rows[ridx][256+lane*4]) = make_float4(v[4],v[5],v[6],v[7]);
    float s = 0.f, s2 = 0.f;
#pragma unroll
    for (int k = 0; k < 8; ++k) { s += v[k]; s2 += v[k]*v[k]; }
    s = wred(s); s2 = wred(s2);
    const float mean = s * (1.f/(float)DD);
    const float var  = s2 * (1.f/(float)DD) - mean*mean;
    if (lane == 0) { mean_s[ridx] = mean; var_s[ridx] = var; }
    if (j >= 4 && P.aud_kpm[rowbase + rl] == 0) {
      const float rstd = rsqrtf(var + EPS);
#pragma unroll
      for (int k = 0; k < 8; ++k) eacc[k] += (v[k]-mean)*rstd*g0[k] + b0[k];
    }
  }

  // per-batch mask counts -> fac/flag (local 0: aud side, local 1: vid side)
  if (local < 2) {
    const int* mk = (local == 0) ? P.aud_kpm : P.vid_kpm;
    int cnt = 0;
#pragma unroll
    for (int q = 0; q < 8; ++q) cnt += (mk[b*TT + q*256 + tid] == 0) ? 1 : 0;
    float fc = wred((float)cnt);
    if (lane == 0) csh[wave] = fc;
    __syncthreads();
    if (tid == 0) {
      const float vc = csh[0]+csh[1]+csh[2]+csh[3];
      P.fs[b*4 + local*2 + 0] = SCALE / fmaxf(vc, 1.f);
      P.fs[b*4 + local*2 + 1] = (vc > 0.f) ? 1.f : 0.f;
    }
  }

  emit_store(eacc, wave, lane, sc2, P.partial + ((size_t)b*LOCALN + local)*DD);

  // ================= 4 phases ==============================================
  for (int p = 0; p < 4; ++p) {
    bbar(P.bar + (3*p + 0)*4 + b);          // partials ready

    // ---- R: nsum[b][d0..d0+3] from 128 tiles ----
    {
      const int tile = tid & 127;
      const int q    = tid >> 7;            // 0: d0/d0+1, 1: d0+2/d0+3
      const int d0   = local * 4;
      const float* pp = P.partial + ((size_t)b*LOCALN + tile)*DD + d0 + q*2;
      float a0 = pp[0], a1 = pp[1];
      a0 = wred(a0); a1 = wred(a1);
      if (lane == 0) { sc2[0][wave*2] = a0; sc2[0][wave*2+1] = a1; }
      __syncthreads();
      if (tid < 4) {
        const int base = (tid >> 1) * 4 + (tid & 1);
        P.nsum[b*DD + d0 + tid] = sc2[0][base] + sc2[0][base + 2];
      }
    }

    bbar(P.bar + (3*p + 1)*4 + b);          // nsum ready

    const int layer = p >> 1;
    const int qv    = ((p & 1) == 0);       // query side is vid on even phases

    // ---- M: ks + m for (b, h=local) ----
    if (local < HH) {
      const int h = local;
      const float* Wk = (qv ? P.Wk_av : P.Wk_va) + (size_t)layer*DD*DD;
      const float* Wq = (qv ? P.Wq_v  : P.Wq_a ) + (size_t)layer*DD*DD;
      const float fac = P.fs[b*4 + (qv ? 0 : 2)];
      float nl[8]; ldf(P.nsum + b*DD, lane, nl);
#pragma unroll 4
      for (int jj = 0; jj < 16; ++jj) {
        const int j = wave*16 + jj;
        const float* wr = Wk + (size_t)(h*64 + j)*DD;
        float w[8]; ldf(wr, lane, w);
        float s = w[0]*nl[0]+w[1]*nl[1]+w[2]*nl[2]+w[3]*nl[3]
                + w[4]*nl[4]+w[5]*nl[5]+w[6]*nl[6]+w[7]*nl[7];
        s = wred(s);
        if (lane == 0) ksl[j] = s * fac;
      }
      __syncthreads();
      float a0 = 0.f, a1 = 0.f;
      const float* wqb = Wq + (size_t)(h*64)*DD;
#pragma unroll 8
      for (int j = 0; j < 64; ++j) {
        const float kk = ksl[j];
        a0 += wqb[(size_t)j*DD + tid]       * kk;
        a1 += wqb[(size_t)j*DD + tid + 256] * kk;
      }
      float* mo = P.mg + ((size_t)b*HH + h)*DD;
      mo[tid]       = a0;
      mo[tid + 256] = a1;
    }

    bbar(P.bar + (3*p + 2)*4 + b);          // m ready

    // ---- U: gate + scale query rows in LDS; emit next phase's partials ----
    {
      const float* qgp = (qv ? P.vid_g : P.aud_g) + (size_t)layer*DD;
      const float* qbp = (qv ? P.vid_b : P.aud_b) + (size_t)layer*DD;
      const float* W1p = (qv ? P.vg_W1 : P.ag_W1) + (size_t)layer*16*HH;
      const float* b1p = (qv ? P.vg_b1 : P.ag_b1) + (size_t)layer*16;
      const float* W2p = (qv ? P.vg_W2 : P.ag_W2) + (size_t)layer*16;
      const float* b2p = (qv ? P.vg_b2 : P.ag_b2) + layer;
      const float flg  = P.fs[b*4 + (qv ? 1 : 3)];

      if (tid < 128)      mlp[tid] = W1p[tid];
      else if (tid < 144) mlp[tid] = b1p[tid - 128];
      else if (tid < 160) mlp[tid] = W2p[tid - 144];
      else if (tid == 160) mlp[tid] = b2p[0];
      __syncthreads();

      float qgv[8], qbv[8];
      ldf(qgp, lane, qgv); ldf(qbp, lane, qbv);
      float egv[8], ebv[8];
      const int* emask = qv ? kvm : kam;
      if (p < 3) {
        const float* egp = qv ? (P.aud_g + (size_t)layer*DD) : (P.vid_g + (size_t)(layer+1)*DD);
        const float* ebp = qv ? (P.aud_b + (size_t)layer*DD) : (P.vid_b + (size_t)(layer+1)*DD);
        ldf(egp, lane, egv); ldf(ebp, lane, ebv);
      }
      float4 mA[HH], mB[HH];
      const float* mb_ = P.mg + (size_t)b*HH*DD;
#pragma unroll
      for (int h = 0; h < HH; ++h) {
        mA[h] = *reinterpret_cast<const float4*>(mb_ + (size_t)h*DD + lane*4);
        mB[h] = *reinterpret_cast<const float4*>(mb_ + (size_t)h*DD + 256 + lane*4);
      }
#pragma unroll
      for (int k = 0; k < 8; ++k) eacc[k] = 0.f;

      for (int jr = 0; jr < 4; ++jr) {
        const int rl   = wave*4 + jr;
        const int ridx = qv ? rl : 16 + rl;
        float v[8];
        float4 a = *reinterpret_cast<const float4*>(&rows[ridx][lane*4]);
        float4 c = *reinterpret_cast<const float4*>(&rows[ridx][256+lane*4]);
        v[0]=a.x; v[1]=a.y; v[2]=a.z; v[3]=a.w; v[4]=c.x; v[5]=c.y; v[6]=c.z; v[7]=c.w;
        const float mean = mean_s[ridx];
        const float var  = var_s[ridx];
        const float rstd = rsqrtf(var + EPS);
        float n[8];
#pragma unroll
        for (int k = 0; k < 8; ++k) n[k] = (v[k]-mean)*rstd*qgv[k] + qbv[k];
        float rel[HH];
#pragma unroll
        for (int h = 0; h < HH; ++h) {
          float s = n[0]*mA[h].x + n[1]*mA[h].y + n[2]*mA[h].z + n[3]*mA[h].w
                  + n[4]*mB[h].x + n[5]*mB[h].y + n[6]*mB[h].z + n[7]*mB[h].w;
          rel[h] = wred(s);
        }
        float z = mlp[160];
#pragma unroll
        for (int e = 0; e < 16; ++e) {
          float h1 = mlp[128 + e];
#pragma unroll
          for (int h = 0; h < HH; ++h) h1 += rel[h]*mlp[e*8+h];
          z += fmaxf(h1, 0.f) * mlp[144+e];
        }
        const float sc = 1.f + flg * (1.f/(1.f + expf(-z)));
#pragma unroll
        for (int k = 0; k < 8; ++k) v[k] *= sc;
        *reinterpret_cast<float4*>(&rows[ridx][lane*4])     = make_float4(v[0],v[1],v[2],v[3]);
        *reinterpret_cast<float4*>(&rows[ridx][256+lane*4]) = make_float4(v[4],v[5],v[6],v[7]);
        const float meany = mean * sc;
        const float vary  = var * sc * sc;
        if (lane == 0) { mean_s[ridx] = meany; var_s[ridx] = vary; }
        if (p < 3 && emask[rl] == 0) {
          const float rstdy = rsqrtf(vary + EPS);
#pragma unroll
          for (int k = 0; k < 8; ++k) eacc[k] += (v[k]-meany)*rstdy*egv[k] + ebv[k];
        }
      }
      if (p < 3) emit_store(eacc, wave, lane, sc2, P.partial + ((size_t)b*LOCALN + local)*DD);
    }
  }

  // ================= writeout ==============================================
#pragma unroll
  for (int j = 0; j < 8; ++j) {
    const int rl   = wave*4 + (j & 3);
    const int ridx = (j < 4) ? rl : 16 + rl;
    float* dst = ((j < 4) ? P.xv : P.xa) + (size_t)(rowbase + rl)*DD;
    float4 a = *reinterpret_cast<const float4*>(&rows[ridx][lane*4]);
    float4 c = *reinterpret_cast<const float4*>(&rows[ridx][256+lane*4]);
    *reinterpret_cast<float4*>(dst + lane*4)       = a;
    *reinterpret_cast<float4*>(dst + 256 + lane*4) = c;
  }
}

// ---------------------------------------------------------------------------
extern "C" void kernel_launch(void* const* d_in, const int* in_sizes, int n_in,
                              void* d_out, int out_size, void* d_ws, size_t ws_size,
                              hipStream_t stream) {
  Params P;
  P.x_vid   = (const float*)d_in[0];
  P.x_aud   = (const float*)d_in[1];
  P.vid_kpm = (const int*)d_in[2];
  P.aud_kpm = (const int*)d_in[3];
  P.Wq_v    = (const float*)d_in[4];
  P.Wk_av   = (const float*)d_in[5];
  P.Wq_a    = (const float*)d_in[6];
  P.Wk_va   = (const float*)d_in[7];
  P.vg_W1 = (const float*)d_in[8];  P.vg_b1 = (const float*)d_in[9];
  P.vg_W2 = (const float*)d_in[10]; P.vg_b2 = (const float*)d_in[11];
  P.ag_W1 = (const float*)d_in[12]; P.ag_b1 = (const float*)d_in[13];
  P.ag_W2 = (const float*)d_in[14]; P.ag_b2 = (const float*)d_in[15];
  P.vid_g = (const float*)d_in[16]; P.vid_b = (const float*)d_in[17];
  P.aud_g = (const float*)d_in[18]; P.aud_b = (const float*)d_in[19];

  const size_t BTD = (size_t)BB * TT * DD;
  P.xv = (float*)d_out;
  P.xa = P.xv + BTD;

  float* w = (float*)d_ws;
  P.partial = w;                                   // 4*128*512 = 262144 floats
  P.nsum    = P.partial + (size_t)BB*LOCALN*DD;    // 2048
  P.mg      = P.nsum + (size_t)BB*DD;              // 16384
  P.fs      = P.mg + (size_t)BB*HH*DD;             // 16
  P.bar     = (unsigned*)(P.fs + 16);              // 48 counters

  hipMemsetAsync((void*)P.bar, 0, 64 * sizeof(unsigned), stream);

  void* kargs[] = { &P };
  hipError_t e = hipLaunchCooperativeKernel((const void*)fused_all,
                                            dim3(NBLK), dim3(256), kargs, 0, stream);
  if (e != hipSuccess) {
    // fallback: plain launch — 512 blocks at 2/CU fit device-wide, so all
    // workgroups are co-resident and the barriers still complete.
    fused_all<<<dim3(NBLK), dim3(256), 0, stream>>>(P);
  }
}

// Round 6
// 138.415 us; speedup vs baseline: 9.0144x; 9.0144x over previous
//
#include <hip/hip_runtime.h>
#include <math.h>

// Problem constants (B,T,D,H,L from the reference)
#define BB 4
#define TT 2048
#define DD 512
#define HH 8
#define NLAYER 2
#define EPS 1e-5f
#define SCALE 0.125f            // dh^-0.5, dh=64

#define NTILE 128               // partial tiles per batch (= emitter blocks/batch)
#define RPW 4                   // rows per wave in emitters (16 rows per block)

__device__ __forceinline__ float wred(float s) {
#pragma unroll
  for (int off = 32; off > 0; off >>= 1) s += __shfl_xor(s, off);
  return s;
}

__device__ __forceinline__ void ldf(const float* p, int lane, float f[8]) {
  float4 a = *reinterpret_cast<const float4*>(p + lane * 4);
  float4 c = *reinterpret_cast<const float4*>(p + 256 + lane * 4);
  f[0]=a.x; f[1]=a.y; f[2]=a.z; f[3]=a.w;
  f[4]=c.x; f[5]=c.y; f[6]=c.z; f[7]=c.w;
}

// ---------------------------------------------------------------------------
// mask_stats (once): fs[b*4+0]=fac_aud, +1=flag_aud, +2=fac_vid, +3=flag_vid
// Grid: 8 blocks (b, side), 256 threads.
// ---------------------------------------------------------------------------
__global__ __launch_bounds__(256) void mask_stats_kernel(
    const int* __restrict__ vid_kpm, const int* __restrict__ aud_kpm,
    float* __restrict__ fs)
{
  const int b    = blockIdx.x >> 1;
  const int side = blockIdx.x & 1;          // 0: aud, 1: vid
  const int tid  = threadIdx.x;
  const int* mk  = side ? vid_kpm : aud_kpm;
  __shared__ float csh[4];
  int cnt = 0;
#pragma unroll
  for (int q = 0; q < 8; ++q) cnt += (mk[b * TT + q * 256 + tid] == 0) ? 1 : 0;
  float fc = wred((float)cnt);
  if ((tid & 63) == 0) csh[tid >> 6] = fc;
  __syncthreads();
  if (tid == 0) {
    const float vc = csh[0] + csh[1] + csh[2] + csh[3];
    fs[b * 4 + side * 2 + 0] = SCALE / fmaxf(vc, 1.f);
    fs[b * 4 + side * 2 + 1] = (vc > 0.f) ? 1.f : 0.f;
  }
}

// ---------------------------------------------------------------------------
// Initial masked LN-sum (phase-0 keys). Grid: BB*NTILE blocks, 256 threads.
// ---------------------------------------------------------------------------
__global__ __launch_bounds__(256) void ln_masked_sum_kernel(
    const float* __restrict__ x,      // (B,T,D)
    const int*   __restrict__ kpm,    // (B,T) flat; nonzero = masked out
    const float* __restrict__ gamma,  // (D)
    const float* __restrict__ beta,   // (D)
    float* __restrict__ partial)      // (B, NTILE, D)
{
  const int bk   = blockIdx.x;
  const int wave = threadIdx.x >> 6;
  const int lane = threadIdx.x & 63;
  const int b    = bk >> 7;
  const int tile = bk & (NTILE - 1);
  const int row0 = bk * 16 + wave * RPW;   // global row = b*TT + t

  __shared__ float lds[4][DD];

  float gv[8], bv[8];
  ldf(gamma, lane, gv); ldf(beta, lane, bv);

  float acc[8] = {0.f,0.f,0.f,0.f,0.f,0.f,0.f,0.f};

  for (int r = 0; r < RPW; ++r) {
    const int row = row0 + r;
    float v[8];
    ldf(x + (size_t)row * DD, lane, v);
    float s = 0.f, s2 = 0.f;
#pragma unroll
    for (int k = 0; k < 8; ++k) { s += v[k]; s2 += v[k] * v[k]; }
    s = wred(s); s2 = wred(s2);
    const float mean = s * (1.f / (float)DD);
    const float var  = s2 * (1.f / (float)DD) - mean * mean;
    const float rstd = rsqrtf(var + EPS);
    if (kpm[row] == 0) {   // wave-uniform branch
#pragma unroll
      for (int k = 0; k < 8; ++k) acc[k] += (v[k] - mean) * rstd * gv[k] + bv[k];
    }
  }

#pragma unroll
  for (int k = 0; k < 4; ++k) {
    lds[wave][lane * 4 + k]       = acc[k];
    lds[wave][256 + lane * 4 + k] = acc[4 + k];
  }
  __syncthreads();

  const int tid = threadIdx.x;
  float s0 = lds[0][tid] + lds[1][tid] + lds[2][tid] + lds[3][tid];
  float s1 = lds[0][tid+256] + lds[1][tid+256] + lds[2][tid+256] + lds[3][tid+256];
  float* p = partial + ((size_t)b * NTILE + tile) * DD;
  p[tid]       = s0;
  p[tid + 256] = s1;
}

// ---------------------------------------------------------------------------
// reduce: nsum[b][d0..d0+3] = sum over 128 tiles. One wave per float4 column.
// Grid: 128 blocks x 256 threads (512 wave-jobs).
// ---------------------------------------------------------------------------
__global__ __launch_bounds__(256) void reduce_kernel(
    const float* __restrict__ partial,  // (B,NTILE,D)
    float* __restrict__ nsum)           // (B,D)
{
  const int w    = blockIdx.x * 4 + (threadIdx.x >> 6);  // 0..511
  const int lane = threadIdx.x & 63;
  const int b    = w >> 7;
  const int d0   = (w & 127) * 4;

  const float* p0 = partial + ((size_t)b * NTILE + lane) * DD + d0;
  float4 a = *reinterpret_cast<const float4*>(p0);
  float4 c = *reinterpret_cast<const float4*>(p0 + (size_t)64 * DD);
  a.x += c.x; a.y += c.y; a.z += c.z; a.w += c.w;
  a.x = wred(a.x); a.y = wred(a.y); a.z = wred(a.z); a.w = wred(a.w);
  if (lane == 0) *reinterpret_cast<float4*>(nsum + (size_t)b * DD + d0) = a;
}

// ---------------------------------------------------------------------------
// ksm: for (b,h,c): ks[j] (16 j's) = fac * Wk[h*64+c*16+j,:] . nsum, then
// m_part[((b*H+h)*4+c)][d] = sum_j Wq[h*64+c*16+j][d] * ks[j].
// Grid: BB*HH*4 = 128 blocks, 256 threads.
// ---------------------------------------------------------------------------
__global__ __launch_bounds__(256) void ksm_kernel(
    const float* __restrict__ nsum,   // (B,D)
    const float* __restrict__ fs,     // (B,4)
    int fofs,                         // 0 (aud keys) or 2 (vid keys)
    const float* __restrict__ Wk,     // (D,D) layer slice
    const float* __restrict__ Wq,     // (D,D) layer slice
    float* __restrict__ m_part)       // (B,H,4,D)
{
  const int blk  = blockIdx.x;
  const int b    = blk >> 5;
  const int h    = (blk >> 2) & 7;
  const int c    = blk & 3;
  const int tid  = threadIdx.x;
  const int wave = tid >> 6;
  const int lane = tid & 63;

  __shared__ float ksl[16];

  const float fac = fs[b * 4 + fofs];
  float nl[8];
  ldf(nsum + (size_t)b * DD, lane, nl);

  // 4 rows per wave
#pragma unroll
  for (int jj = 0; jj < 4; ++jj) {
    const int j = wave * 4 + jj;                    // 0..15 within chunk
    const float* wr = Wk + (size_t)(h * 64 + c * 16 + j) * DD;
    float w[8];
    ldf(wr, lane, w);
    float s = w[0]*nl[0]+w[1]*nl[1]+w[2]*nl[2]+w[3]*nl[3]
            + w[4]*nl[4]+w[5]*nl[5]+w[6]*nl[6]+w[7]*nl[7];
    s = wred(s);
    if (lane == 0) ksl[j] = s * fac;
  }
  __syncthreads();

  float a0 = 0.f, a1 = 0.f;
  const float* base = Wq + (size_t)(h * 64 + c * 16) * DD;
#pragma unroll
  for (int j = 0; j < 16; ++j) {
    const float kk = ksl[j];
    a0 += base[(size_t)j * DD + tid]       * kk;
    a1 += base[(size_t)j * DD + tid + 256] * kk;
  }
  float* mo = m_part + (((size_t)b * HH + h) * 4 + c) * DD;
  mo[tid]       = a0;
  mo[tid + 256] = a1;
}

// ---------------------------------------------------------------------------
// update: per-row LN, rel[h] = n . m[b,h,:] (m = sum of 4 parts, hoisted),
// gate MLP, out = x*(1+flag*sig(z)); fused emit of next phase's partials.
// Grid: BB*NTILE = 512 blocks, 256 threads.
// ---------------------------------------------------------------------------
__global__ __launch_bounds__(256) void update_kernel(
    const float* __restrict__ xin,     // (B,T,D)
    const float* __restrict__ gamma,   // (D)   query-side LN
    const float* __restrict__ beta,    // (D)
    const float* __restrict__ m_part,  // (B,H,4,D)
    const float* __restrict__ fs,      // (B,4)
    int flofs,                         // flag offset: 1 (aud) or 3 (vid)
    const float* __restrict__ W1,      // (16,8)
    const float* __restrict__ b1,      // (16)
    const float* __restrict__ W2,      // (16)
    const float* __restrict__ b2,      // (1)
    const int*   __restrict__ kpm_next,// (B,T) flat — next phase's KEY mask
    const float* __restrict__ gnext,   // (D)
    const float* __restrict__ bnext,   // (D)
    float* __restrict__ xout,          // (B,T,D)
    float* __restrict__ partial,       // (B,NTILE,D)
    int emit)
{
  const int bk   = blockIdx.x;
  const int wave = threadIdx.x >> 6;
  const int lane = threadIdx.x & 63;
  const int b    = bk >> 7;
  const int tile = bk & (NTILE - 1);
  const int row0 = bk * 16 + wave * RPW;

  __shared__ float lds[4][DD];

  float gv[8], bv[8], gnv[8], bnv[8];
  ldf(gamma, lane, gv); ldf(beta, lane, bv);
  if (emit) { ldf(gnext, lane, gnv); ldf(bnext, lane, bnv); }

  // hoist m fragments, summing the 4 partials
  float4 mA[HH], mB[HH];
#pragma unroll
  for (int h = 0; h < HH; ++h) {
    const float* mp = m_part + ((size_t)b * HH + h) * 4 * DD;
    float4 s0 = *reinterpret_cast<const float4*>(mp + lane * 4);
    float4 s1 = *reinterpret_cast<const float4*>(mp + 256 + lane * 4);
#pragma unroll
    for (int c = 1; c < 4; ++c) {
      float4 t0 = *reinterpret_cast<const float4*>(mp + (size_t)c * DD + lane * 4);
      float4 t1 = *reinterpret_cast<const float4*>(mp + (size_t)c * DD + 256 + lane * 4);
      s0.x += t0.x; s0.y += t0.y; s0.z += t0.z; s0.w += t0.w;
      s1.x += t1.x; s1.y += t1.y; s1.z += t1.z; s1.w += t1.w;
    }
    mA[h] = s0; mB[h] = s1;
  }
  const float flg = fs[b * 4 + flofs];

  float eacc[8] = {0.f,0.f,0.f,0.f,0.f,0.f,0.f,0.f};

  for (int r = 0; r < RPW; ++r) {
    const int row = row0 + r;
    float v[8];
    ldf(xin + (size_t)row * DD, lane, v);

    float s = 0.f, s2 = 0.f;
#pragma unroll
    for (int k = 0; k < 8; ++k) { s += v[k]; s2 += v[k] * v[k]; }
    s = wred(s); s2 = wred(s2);
    const float mean = s * (1.f / (float)DD);
    const float var  = s2 * (1.f / (float)DD) - mean * mean;
    const float rstd = rsqrtf(var + EPS);

    float n[8];
#pragma unroll
    for (int k = 0; k < 8; ++k) n[k] = (v[k] - mean) * rstd * gv[k] + bv[k];

    float rel[HH];
#pragma unroll
    for (int h = 0; h < HH; ++h) {
      float p = n[0]*mA[h].x + n[1]*mA[h].y + n[2]*mA[h].z + n[3]*mA[h].w
              + n[4]*mB[h].x + n[5]*mB[h].y + n[6]*mB[h].z + n[7]*mB[h].w;
      rel[h] = wred(p);
    }

    float z = b2[0];
#pragma unroll
    for (int e = 0; e < 16; ++e) {
      float h1 = b1[e];
#pragma unroll
      for (int h = 0; h < HH; ++h) h1 += rel[h] * W1[e * HH + h];
      z += fmaxf(h1, 0.f) * W2[e];
    }
    const float sc = 1.f + flg * (1.f / (1.f + expf(-z)));

    float* orow = xout + (size_t)row * DD;
    *reinterpret_cast<float4*>(orow + lane * 4) =
        make_float4(v[0]*sc, v[1]*sc, v[2]*sc, v[3]*sc);
    *reinterpret_cast<float4*>(orow + 256 + lane * 4) =
        make_float4(v[4]*sc, v[5]*sc, v[6]*sc, v[7]*sc);

    if (emit && kpm_next[row] == 0) {   // wave-uniform
      const float mean_y = mean * sc;
      const float rstd_y = rsqrtf(var * sc * sc + EPS);
#pragma unroll
      for (int k = 0; k < 8; ++k)
        eacc[k] += (v[k]*sc - mean_y) * rstd_y * gnv[k] + bnv[k];
    }
  }

  if (emit) {
#pragma unroll
    for (int k = 0; k < 4; ++k) {
      lds[wave][lane * 4 + k]       = eacc[k];
      lds[wave][256 + lane * 4 + k] = eacc[4 + k];
    }
    __syncthreads();
    const int tid = threadIdx.x;
    float s0 = lds[0][tid] + lds[1][tid] + lds[2][tid] + lds[3][tid];
    float s1 = lds[0][tid+256] + lds[1][tid+256] + lds[2][tid+256] + lds[3][tid+256];
    float* p = partial + ((size_t)b * NTILE + tile) * DD;
    p[tid]       = s0;
    p[tid + 256] = s1;
  }
}

// ---------------------------------------------------------------------------
extern "C" void kernel_launch(void* const* d_in, const int* in_sizes, int n_in,
                              void* d_out, int out_size, void* d_ws, size_t ws_size,
                              hipStream_t stream) {
  const float* x_vid = (const float*)d_in[0];
  const float* x_aud = (const float*)d_in[1];
  const int* vid_kpm = (const int*)d_in[2];
  const int* aud_kpm = (const int*)d_in[3];
  const float* Wq_vid         = (const float*)d_in[4];
  const float* Wk_aud_for_vid = (const float*)d_in[5];
  const float* Wq_aud         = (const float*)d_in[6];
  const float* Wk_vid_for_aud = (const float*)d_in[7];
  const float* vg_W1 = (const float*)d_in[8];
  const float* vg_b1 = (const float*)d_in[9];
  const float* vg_W2 = (const float*)d_in[10];
  const float* vg_b2 = (const float*)d_in[11];
  const float* ag_W1 = (const float*)d_in[12];
  const float* ag_b1 = (const float*)d_in[13];
  const float* ag_W2 = (const float*)d_in[14];
  const float* ag_b2 = (const float*)d_in[15];
  const float* vid_ln_g = (const float*)d_in[16];
  const float* vid_ln_b = (const float*)d_in[17];
  const float* aud_ln_g = (const float*)d_in[18];
  const float* aud_ln_b = (const float*)d_in[19];

  const size_t BTD = (size_t)BB * TT * DD;
  float* xv = (float*)d_out;        // working/output x_vid
  float* xa = xv + BTD;             // working/output x_aud

  float* partial = (float*)d_ws;                         // B*NTILE*D (1 MB)
  float* nsum    = partial + (size_t)BB * NTILE * DD;    // B*D
  float* m_part  = nsum + (size_t)BB * DD;               // B*H*4*D
  float* fs      = m_part + (size_t)BB * HH * 4 * DD;    // B*4

  const size_t WW = (size_t)DD * DD;  // per-layer weight matrix stride

  mask_stats_kernel<<<BB * 2, 256, 0, stream>>>(vid_kpm, aud_kpm, fs);
  ln_masked_sum_kernel<<<BB * NTILE, 256, 0, stream>>>(
      x_aud, aud_kpm, vid_ln_g, vid_ln_b, partial);

  for (int i = 0; i < NLAYER; ++i) {
    const float* srcV = (i == 0) ? x_vid : xv;
    const float* srcA = (i == 0) ? x_aud : xa;
    const int last = (i == NLAYER - 1);
    const size_t inext = last ? (size_t)i : (size_t)(i + 1);

    // --- Phase A: vid queries, aud keys (vid_ln both sides) ---
    reduce_kernel<<<128, 256, 0, stream>>>(partial, nsum);
    ksm_kernel<<<128, 256, 0, stream>>>(
        nsum, fs, 0, Wk_aud_for_vid + (size_t)i * WW, Wq_vid + (size_t)i * WW, m_part);
    update_kernel<<<BB * NTILE, 256, 0, stream>>>(
        srcV, vid_ln_g + (size_t)i * DD, vid_ln_b + (size_t)i * DD, m_part, fs, 1,
        vg_W1 + (size_t)i * 16 * HH, vg_b1 + (size_t)i * 16,
        vg_W2 + (size_t)i * 16, vg_b2 + i,
        vid_kpm, aud_ln_g + (size_t)i * DD, aud_ln_b + (size_t)i * DD,
        xv, partial, 1);

    // --- Phase B: aud queries, updated-vid keys (aud_ln both sides) ---
    reduce_kernel<<<128, 256, 0, stream>>>(partial, nsum);
    ksm_kernel<<<128, 256, 0, stream>>>(
        nsum, fs, 2, Wk_vid_for_aud + (size_t)i * WW, Wq_aud + (size_t)i * WW, m_part);
    update_kernel<<<BB * NTILE, 256, 0, stream>>>(
        srcA, aud_ln_g + (size_t)i * DD, aud_ln_b + (size_t)i * DD, m_part, fs, 3,
        ag_W1 + (size_t)i * 16 * HH, ag_b1 + (size_t)i * 16,
        ag_W2 + (size_t)i * 16, ag_b2 + i,
        aud_kpm, vid_ln_g + inext * DD, vid_ln_b + inext * DD,
        xa, partial, last ? 0 : 1);
  }
}

// Round 7
// 63.194 us; speedup vs baseline: 19.7447x; 2.1903x over previous
//
#include <hip/hip_runtime.h>
#include <math.h>

// Problem constants (B,T,D,H,L from the reference)
#define BB 4
#define TT 2048
#define DD 512
#define HH 8
#define EPS 1e-5f
#define SCALE 0.125f            // dh^-0.5, dh=64
#define WW ((size_t)DD * DD)

// Key algebraic identity used throughout: every phase update is x' = x * sc
// (per-row scalar, sc in [1,2]), and LayerNorm is scale-invariant, so the
// normalized rows n_t of the CURRENT tensor at any phase equal those of the
// ORIGINAL tensor (up to an eps*(1-1/sc^2) wobble ~1e-5). Hence:
//   - key-side masked LN-sums for all 4 phases derive from one masked sum of
//     normalized original rows per side:  nsum_p = S*gamma_p + cnt*beta_p
//   - query-side LN in every phase uses original-row n_t
//   - gates compose multiplicatively: out = x*(1+g_layer0)*(1+g_layer1)
// This removes ALL sequential dependencies between the 4 phases.

__device__ __forceinline__ float wred(float s) {
#pragma unroll
  for (int o = 32; o > 0; o >>= 1) s += __shfl_xor(s, o);
  return s;
}

__device__ __forceinline__ void ldf(const float* p, int lane, float f[8]) {
  float4 a = *reinterpret_cast<const float4*>(p + lane * 4);
  float4 c = *reinterpret_cast<const float4*>(p + 256 + lane * 4);
  f[0]=a.x; f[1]=a.y; f[2]=a.z; f[3]=a.w;
  f[4]=c.x; f[5]=c.y; f[6]=c.z; f[7]=c.w;
}

// ---------------------------------------------------------------------------
// K1: masked sum of normalized rows, both sides.
// Grid: 2*4*64 = 512 blocks, 256 threads; 32 rows/block (8 per wave).
// partial[(s*4+b)*64 + tile][d]
// ---------------------------------------------------------------------------
__global__ __launch_bounds__(256) void sums_kernel(
    const float* __restrict__ xv, const float* __restrict__ xa,
    const int* __restrict__ vkpm, const int* __restrict__ akpm,
    float* __restrict__ partial)
{
  const int blk  = blockIdx.x;
  const int s    = blk >> 8;
  const int b    = (blk >> 6) & 3;
  const int tile = blk & 63;
  const int wave = threadIdx.x >> 6, lane = threadIdx.x & 63;
  const float* x  = s ? xa : xv;
  const int* kpm  = s ? akpm : vkpm;
  const int row0  = b * TT + tile * 32 + wave * 8;

  __shared__ float lds[4][DD];

  float acc[8] = {0.f,0.f,0.f,0.f,0.f,0.f,0.f,0.f};
  for (int r = 0; r < 8; ++r) {
    const int row = row0 + r;
    float v[8]; ldf(x + (size_t)row * DD, lane, v);
    float s1 = 0.f, s2 = 0.f;
#pragma unroll
    for (int k = 0; k < 8; ++k) { s1 += v[k]; s2 += v[k]*v[k]; }
    s1 = wred(s1); s2 = wred(s2);
    const float mean = s1 * (1.f / (float)DD);
    const float var  = s2 * (1.f / (float)DD) - mean * mean;
    const float rstd = rsqrtf(var + EPS);
    if (kpm[row] == 0) {          // wave-uniform
#pragma unroll
      for (int k = 0; k < 8; ++k) acc[k] += (v[k] - mean) * rstd;
    }
  }
#pragma unroll
  for (int k = 0; k < 4; ++k) {
    lds[wave][lane*4+k]       = acc[k];
    lds[wave][256+lane*4+k]   = acc[4+k];
  }
  __syncthreads();
  const int tid = threadIdx.x;
  float s0 = lds[0][tid] + lds[1][tid] + lds[2][tid] + lds[3][tid];
  float s1 = lds[0][tid+256] + lds[1][tid+256] + lds[2][tid+256] + lds[3][tid+256];
  float* p = partial + ((size_t)(s*4 + b) * 64 + tile) * DD;
  p[tid]       = s0;
  p[tid + 256] = s1;
}

// ---------------------------------------------------------------------------
// K2: S[sb][d] = sum over 64 tiles (one wave per 4 d's, lane = tile).
// Blocks 0..7 additionally compute fs[sb] = {fac, flag, cnt}.
// Grid: 256 blocks, 256 threads.
// ---------------------------------------------------------------------------
__global__ __launch_bounds__(256) void reduce_kernel(
    const float* __restrict__ partial,
    const int* __restrict__ vkpm, const int* __restrict__ akpm,
    float* __restrict__ S, float* __restrict__ fs)
{
  const int tid = threadIdx.x, wave = tid >> 6, lane = tid & 63;
  const int job = blockIdx.x * 4 + wave;        // 0..1023
  const int sb  = job >> 7;                     // (side*4+b)
  const int d0  = (job & 127) * 4;
  __shared__ float csh[4];

  const float* p0 = partial + ((size_t)sb * 64 + lane) * DD + d0;
  float4 a = *reinterpret_cast<const float4*>(p0);
  a.x = wred(a.x); a.y = wred(a.y); a.z = wred(a.z); a.w = wred(a.w);
  if (lane == 0) *reinterpret_cast<float4*>(S + (size_t)sb * DD + d0) = a;

  if (blockIdx.x < 8) {           // block-uniform branch
    const int s = blockIdx.x >> 2, b = blockIdx.x & 3;
    const int* mk = s ? akpm : vkpm;
    int cnt = 0;
#pragma unroll
    for (int q = 0; q < 8; ++q) cnt += (mk[b*TT + q*256 + tid] == 0) ? 1 : 0;
    float fc = wred((float)cnt);
    if (lane == 0) csh[wave] = fc;
    __syncthreads();
    if (tid == 0) {
      const float vc = csh[0] + csh[1] + csh[2] + csh[3];
      fs[blockIdx.x*4 + 0] = SCALE / fmaxf(vc, 1.f);
      fs[blockIdx.x*4 + 1] = (vc > 0.f) ? 1.f : 0.f;
      fs[blockIdx.x*4 + 2] = vc;
    }
  }
}

// ---------------------------------------------------------------------------
// K3: all 4 phases' m vectors.  Block = (p, b, h).
// nsum = S_key*gamma_p + cnt*beta_p (on the fly);
// ks[j] = fac * Wk[h*64+j,:] . nsum;  m[p,b,h,d] = sum_j Wq[h*64+j][d]*ks[j].
// Grid: 4*4*8 = 128 blocks, 256 threads.
// ---------------------------------------------------------------------------
__global__ __launch_bounds__(256) void mphase_kernel(
    const float* __restrict__ S, const float* __restrict__ fs,
    const float* __restrict__ Wq_v, const float* __restrict__ Wk_av,
    const float* __restrict__ Wq_a, const float* __restrict__ Wk_va,
    const float* __restrict__ vid_g, const float* __restrict__ vid_b,
    const float* __restrict__ aud_g, const float* __restrict__ aud_b,
    float* __restrict__ m)          // (4,4,8,512)
{
  const int blk = blockIdx.x;
  const int p = blk >> 5, b = (blk >> 3) & 3, h = blk & 7;
  const int layer = p >> 1;
  const int isA = ((p & 1) == 0);   // A phases: vid queries, aud keys
  const int tid = threadIdx.x, wave = tid >> 6, lane = tid & 63;
  __shared__ float ksl[64];

  const int ksb = (isA ? 1 : 0) * 4 + b;        // key mask side
  const float* g  = (isA ? vid_g : aud_g) + (size_t)layer * DD;
  const float* be = (isA ? vid_b : aud_b) + (size_t)layer * DD;
  const float* Wk = (isA ? Wk_av : Wk_va) + (size_t)layer * WW;
  const float* Wq = (isA ? Wq_v  : Wq_a ) + (size_t)layer * WW;
  const float fac  = fs[ksb*4 + 0];
  const float cntf = fs[ksb*4 + 2];

  float gv[8], bv[8], sv[8], nl[8];
  ldf(g, lane, gv); ldf(be, lane, bv); ldf(S + (size_t)ksb * DD, lane, sv);
#pragma unroll
  for (int k = 0; k < 8; ++k) nl[k] = sv[k]*gv[k] + cntf*bv[k];

#pragma unroll 4
  for (int jj = 0; jj < 16; ++jj) {
    const int j = wave * 16 + jj;
    float w[8]; ldf(Wk + (size_t)(h*64 + j) * DD, lane, w);
    float sdot = w[0]*nl[0]+w[1]*nl[1]+w[2]*nl[2]+w[3]*nl[3]
               + w[4]*nl[4]+w[5]*nl[5]+w[6]*nl[6]+w[7]*nl[7];
    sdot = wred(sdot);
    if (lane == 0) ksl[j] = sdot * fac;
  }
  __syncthreads();

  float a0 = 0.f, a1 = 0.f;
  const float* base = Wq + (size_t)(h*64) * DD;
#pragma unroll 16
  for (int j = 0; j < 64; ++j) {
    const float kk = ksl[j];
    a0 += base[(size_t)j*DD + tid]       * kk;
    a1 += base[(size_t)j*DD + tid + 256] * kk;
  }
  float* mo = m + (((size_t)p*4 + b)*8 + h) * DD;
  mo[tid]       = a0;
  mo[tid + 256] = a1;
}

// ---------------------------------------------------------------------------
// K4: final gates + output.  Block = 16 rows of one side.
// Per row: n_t from original stats; for each layer l: rel[h] = LN_l(n).m[p],
// gate MLP -> sc *= (1+flag*sig(z)); out = x * sc_total.
// Grid: 2*4*128 = 1024 blocks, 256 threads.
// ---------------------------------------------------------------------------
__global__ __launch_bounds__(256) void final_kernel(
    const float* __restrict__ xv_in, const float* __restrict__ xa_in,
    const float* __restrict__ m, const float* __restrict__ fs,
    const float* __restrict__ vg_W1, const float* __restrict__ vg_b1,
    const float* __restrict__ vg_W2, const float* __restrict__ vg_b2,
    const float* __restrict__ ag_W1, const float* __restrict__ ag_b1,
    const float* __restrict__ ag_W2, const float* __restrict__ ag_b2,
    const float* __restrict__ vid_g, const float* __restrict__ vid_b,
    const float* __restrict__ aud_g, const float* __restrict__ aud_b,
    float* __restrict__ out_v, float* __restrict__ out_a)
{
  const int blk = blockIdx.x;
  const int s = blk >> 9, b = (blk >> 7) & 3, tile = blk & 127;
  const int tid = threadIdx.x, wave = tid >> 6, lane = tid & 63;
  const float* x = s ? xa_in : xv_in;
  float* out     = s ? out_a : out_v;
  const int row0 = b * TT + tile * 16 + wave * 4;

  __shared__ float mlp[161];

  float v[4][8], mean[4], rstd[4];
#pragma unroll
  for (int r = 0; r < 4; ++r) {
    ldf(x + (size_t)(row0 + r) * DD, lane, v[r]);
    float s1 = 0.f, s2 = 0.f;
#pragma unroll
    for (int k = 0; k < 8; ++k) { s1 += v[r][k]; s2 += v[r][k]*v[r][k]; }
    s1 = wred(s1); s2 = wred(s2);
    mean[r] = s1 * (1.f / (float)DD);
    const float var = s2 * (1.f / (float)DD) - mean[r]*mean[r];
    rstd[r] = rsqrtf(var + EPS);
  }
  float sc[4] = {1.f, 1.f, 1.f, 1.f};

  for (int l = 0; l < 2; ++l) {
    const int p = l*2 + s;                      // s=0: phases 0,2; s=1: 1,3
    const float* W1p = (s ? ag_W1 : vg_W1) + (size_t)l * 128;
    const float* b1p = (s ? ag_b1 : vg_b1) + (size_t)l * 16;
    const float* W2p = (s ? ag_W2 : vg_W2) + (size_t)l * 16;
    const float* b2p = (s ? ag_b2 : vg_b2) + l;
    __syncthreads();
    if (tid < 128)       mlp[tid] = W1p[tid];
    else if (tid < 144)  mlp[tid] = b1p[tid - 128];
    else if (tid < 160)  mlp[tid] = W2p[tid - 144];
    else if (tid == 160) mlp[160] = b2p[0];
    __syncthreads();

    float gq[8], bq[8];
    ldf((s ? aud_g : vid_g) + (size_t)l * DD, lane, gq);
    ldf((s ? aud_b : vid_b) + (size_t)l * DD, lane, bq);
    const float flag = fs[(((s ? 0 : 1) * 4) + b) * 4 + 1];   // key-mask side

    float4 mA[HH], mB[HH];
    const float* mb_ = m + (((size_t)p*4 + b) * 8) * DD;
#pragma unroll
    for (int h = 0; h < HH; ++h) {
      mA[h] = *reinterpret_cast<const float4*>(mb_ + (size_t)h*DD + lane*4);
      mB[h] = *reinterpret_cast<const float4*>(mb_ + (size_t)h*DD + 256 + lane*4);
    }

#pragma unroll
    for (int r = 0; r < 4; ++r) {
      float n[8];
#pragma unroll
      for (int k = 0; k < 8; ++k) n[k] = (v[r][k] - mean[r]) * rstd[r] * gq[k] + bq[k];
      float rel[HH];
#pragma unroll
      for (int h = 0; h < HH; ++h) {
        float d = n[0]*mA[h].x + n[1]*mA[h].y + n[2]*mA[h].z + n[3]*mA[h].w
                + n[4]*mB[h].x + n[5]*mB[h].y + n[6]*mB[h].z + n[7]*mB[h].w;
        rel[h] = wred(d);
      }
      float z = mlp[160];
#pragma unroll
      for (int e = 0; e < 16; ++e) {
        float h1 = mlp[128 + e];
#pragma unroll
        for (int h = 0; h < HH; ++h) h1 += rel[h] * mlp[e*8 + h];
        z += fmaxf(h1, 0.f) * mlp[144 + e];
      }
      sc[r] *= 1.f + flag * (1.f / (1.f + expf(-z)));
    }
  }

#pragma unroll
  for (int r = 0; r < 4; ++r) {
    float* orow = out + (size_t)(row0 + r) * DD;
    *reinterpret_cast<float4*>(orow + lane*4) =
        make_float4(v[r][0]*sc[r], v[r][1]*sc[r], v[r][2]*sc[r], v[r][3]*sc[r]);
    *reinterpret_cast<float4*>(orow + 256 + lane*4) =
        make_float4(v[r][4]*sc[r], v[r][5]*sc[r], v[r][6]*sc[r], v[r][7]*sc[r]);
  }
}

// ---------------------------------------------------------------------------
extern "C" void kernel_launch(void* const* d_in, const int* in_sizes, int n_in,
                              void* d_out, int out_size, void* d_ws, size_t ws_size,
                              hipStream_t stream) {
  const float* x_vid = (const float*)d_in[0];
  const float* x_aud = (const float*)d_in[1];
  const int* vid_kpm = (const int*)d_in[2];
  const int* aud_kpm = (const int*)d_in[3];
  const float* Wq_vid         = (const float*)d_in[4];
  const float* Wk_aud_for_vid = (const float*)d_in[5];
  const float* Wq_aud         = (const float*)d_in[6];
  const float* Wk_vid_for_aud = (const float*)d_in[7];
  const float* vg_W1 = (const float*)d_in[8];
  const float* vg_b1 = (const float*)d_in[9];
  const float* vg_W2 = (const float*)d_in[10];
  const float* vg_b2 = (const float*)d_in[11];
  const float* ag_W1 = (const float*)d_in[12];
  const float* ag_b1 = (const float*)d_in[13];
  const float* ag_W2 = (const float*)d_in[14];
  const float* ag_b2 = (const float*)d_in[15];
  const float* vid_ln_g = (const float*)d_in[16];
  const float* vid_ln_b = (const float*)d_in[17];
  const float* aud_ln_g = (const float*)d_in[18];
  const float* aud_ln_b = (const float*)d_in[19];

  const size_t BTD = (size_t)BB * TT * DD;
  float* out_v = (float*)d_out;
  float* out_a = out_v + BTD;

  float* partial = (float*)d_ws;                       // 2*4*64*512 = 1 MB
  float* S       = partial + (size_t)8 * 64 * DD;      // 2*4*512
  float* fs      = S + (size_t)8 * DD;                 // 8*4
  float* m       = fs + 32;                            // 4*4*8*512 = 256 KB

  sums_kernel<<<512, 256, 0, stream>>>(x_vid, x_aud, vid_kpm, aud_kpm, partial);
  reduce_kernel<<<256, 256, 0, stream>>>(partial, vid_kpm, aud_kpm, S, fs);
  mphase_kernel<<<128, 256, 0, stream>>>(
      S, fs, Wq_vid, Wk_aud_for_vid, Wq_aud, Wk_vid_for_aud,
      vid_ln_g, vid_ln_b, aud_ln_g, aud_ln_b, m);
  final_kernel<<<1024, 256, 0, stream>>>(
      x_vid, x_aud, m, fs,
      vg_W1, vg_b1, vg_W2, vg_b2, ag_W1, ag_b1, ag_W2, ag_b2,
      vid_ln_g, vid_ln_b, aud_ln_g, aud_ln_b, out_v, out_a);
}

// Round 8
// 50.900 us; speedup vs baseline: 24.5134x; 1.2415x over previous
//
#include <hip/hip_runtime.h>
#include <math.h>

// Problem constants (B,T,D,H,L from the reference)
#define BB 4
#define TT 2048
#define DD 512
#define HH 8
#define EPS 1e-5f
#define SCALE 0.125f            // dh^-0.5, dh=64
#define WW ((size_t)DD * DD)

// Algebra (verified R7): phase updates are per-row scalings; LN is
// scale-invariant, so all 4 phases decouple:
//   key-side LN-sums for every phase derive from one masked sum S of
//   normalized original rows per side; gates compose multiplicatively.
// R8 additions:
//   rel[h] = n . m[h], n = (v-mean)*rstd*g + be
//          = rstd*( v.(g*m) - mean*sum(g*m) ) + sum(be*m)
//   so final dots RAW v against mp = g*m with scalars sm = sum(mp),
//   c = sum(be*m): no per-layer LN application in the hot kernel.

__device__ __forceinline__ float wred(float s) {
#pragma unroll
  for (int o = 32; o > 0; o >>= 1) s += __shfl_xor(s, o);
  return s;
}

__device__ __forceinline__ void ldf(const float* p, int lane, float f[8]) {
  float4 a = *reinterpret_cast<const float4*>(p + lane * 4);
  float4 c = *reinterpret_cast<const float4*>(p + 256 + lane * 4);
  f[0]=a.x; f[1]=a.y; f[2]=a.z; f[3]=a.w;
  f[4]=c.x; f[5]=c.y; f[6]=c.z; f[7]=c.w;
}

// ---------------------------------------------------------------------------
// K1: masked sum of normalized rows, both sides.
// Grid: 512 blocks, 256 threads; 32 rows/block. partial[(s*4+b)*64+tile][d]
// ---------------------------------------------------------------------------
__global__ __launch_bounds__(256) void sums_kernel(
    const float* __restrict__ xv, const float* __restrict__ xa,
    const int* __restrict__ vkpm, const int* __restrict__ akpm,
    float* __restrict__ partial)
{
  const int blk  = blockIdx.x;
  const int s    = blk >> 8;
  const int b    = (blk >> 6) & 3;
  const int tile = blk & 63;
  const int wave = threadIdx.x >> 6, lane = threadIdx.x & 63;
  const float* x  = s ? xa : xv;
  const int* kpm  = s ? akpm : vkpm;
  const int row0  = b * TT + tile * 32 + wave * 8;

  __shared__ float lds[4][DD];

  float acc[8] = {0.f,0.f,0.f,0.f,0.f,0.f,0.f,0.f};
  for (int r = 0; r < 8; ++r) {
    const int row = row0 + r;
    float v[8]; ldf(x + (size_t)row * DD, lane, v);
    float s1 = 0.f, s2 = 0.f;
#pragma unroll
    for (int k = 0; k < 8; ++k) { s1 += v[k]; s2 += v[k]*v[k]; }
    s1 = wred(s1); s2 = wred(s2);
    const float mean = s1 * (1.f / (float)DD);
    const float var  = s2 * (1.f / (float)DD) - mean * mean;
    const float rstd = rsqrtf(var + EPS);
    if (kpm[row] == 0) {          // wave-uniform
#pragma unroll
      for (int k = 0; k < 8; ++k) acc[k] += (v[k] - mean) * rstd;
    }
  }
#pragma unroll
  for (int k = 0; k < 4; ++k) {
    lds[wave][lane*4+k]       = acc[k];
    lds[wave][256+lane*4+k]   = acc[4+k];
  }
  __syncthreads();
  const int tid = threadIdx.x;
  float s0 = lds[0][tid] + lds[1][tid] + lds[2][tid] + lds[3][tid];
  float s1 = lds[0][tid+256] + lds[1][tid+256] + lds[2][tid+256] + lds[3][tid+256];
  float* p = partial + ((size_t)(s*4 + b) * 64 + tile) * DD;
  p[tid]       = s0;
  p[tid + 256] = s1;
}

// ---------------------------------------------------------------------------
// K2: S[sb][d] = sum over 64 tiles; blocks 0..7 also fs = {fac, flag, cnt}.
// Grid: 256 blocks, 256 threads.
// ---------------------------------------------------------------------------
__global__ __launch_bounds__(256) void reduce_kernel(
    const float* __restrict__ partial,
    const int* __restrict__ vkpm, const int* __restrict__ akpm,
    float* __restrict__ S, float* __restrict__ fs)
{
  const int tid = threadIdx.x, wave = tid >> 6, lane = tid & 63;
  const int job = blockIdx.x * 4 + wave;        // 0..1023
  const int sb  = job >> 7;                     // (side*4+b)
  const int d0  = (job & 127) * 4;
  __shared__ float csh[4];

  const float* p0 = partial + ((size_t)sb * 64 + lane) * DD + d0;
  float4 a = *reinterpret_cast<const float4*>(p0);
  a.x = wred(a.x); a.y = wred(a.y); a.z = wred(a.z); a.w = wred(a.w);
  if (lane == 0) *reinterpret_cast<float4*>(S + (size_t)sb * DD + d0) = a;

  if (blockIdx.x < 8) {           // block-uniform branch
    const int s = blockIdx.x >> 2, b = blockIdx.x & 3;
    const int* mk = s ? akpm : vkpm;
    int cnt = 0;
#pragma unroll
    for (int q = 0; q < 8; ++q) cnt += (mk[b*TT + q*256 + tid] == 0) ? 1 : 0;
    float fc = wred((float)cnt);
    if (lane == 0) csh[wave] = fc;
    __syncthreads();
    if (tid == 0) {
      const float vc = csh[0] + csh[1] + csh[2] + csh[3];
      fs[blockIdx.x*4 + 0] = SCALE / fmaxf(vc, 1.f);
      fs[blockIdx.x*4 + 1] = (vc > 0.f) ? 1.f : 0.f;
      fs[blockIdx.x*4 + 2] = vc;
    }
  }
}

// ---------------------------------------------------------------------------
// K3: all 4 phases' m vectors, emitted pre-transformed:
//   mp[p,b,h,d] = g_p[d]*m[d];  sm[p,b,h] = sum_d mp;  c[p,b,h] = sum_d be_p[d]*m[d]
// Grid: 4*4*8 = 128 blocks, 256 threads.
// ---------------------------------------------------------------------------
__global__ __launch_bounds__(256) void mphase_kernel(
    const float* __restrict__ S, const float* __restrict__ fs,
    const float* __restrict__ Wq_v, const float* __restrict__ Wk_av,
    const float* __restrict__ Wq_a, const float* __restrict__ Wk_va,
    const float* __restrict__ vid_g, const float* __restrict__ vid_b,
    const float* __restrict__ aud_g, const float* __restrict__ aud_b,
    float* __restrict__ mp,         // (4,4,8,512)
    float* __restrict__ cv,         // (4,4,8)
    float* __restrict__ smv)        // (4,4,8)
{
  const int blk = blockIdx.x;
  const int p = blk >> 5, b = (blk >> 3) & 3, h = blk & 7;
  const int layer = p >> 1;
  const int isA = ((p & 1) == 0);   // A phases: vid queries, aud keys
  const int tid = threadIdx.x, wave = tid >> 6, lane = tid & 63;
  __shared__ float ksl[64];
  __shared__ float cs2[4], ss2[4];

  const int ksb = (isA ? 1 : 0) * 4 + b;        // key mask side
  const float* g  = (isA ? vid_g : aud_g) + (size_t)layer * DD;
  const float* be = (isA ? vid_b : aud_b) + (size_t)layer * DD;
  const float* Wk = (isA ? Wk_av : Wk_va) + (size_t)layer * WW;
  const float* Wq = (isA ? Wq_v  : Wq_a ) + (size_t)layer * WW;
  const float fac  = fs[ksb*4 + 0];
  const float cntf = fs[ksb*4 + 2];

  float gv[8], bv[8], sv[8], nl[8];
  ldf(g, lane, gv); ldf(be, lane, bv); ldf(S + (size_t)ksb * DD, lane, sv);
#pragma unroll
  for (int k = 0; k < 8; ++k) nl[k] = sv[k]*gv[k] + cntf*bv[k];

#pragma unroll 4
  for (int jj = 0; jj < 16; ++jj) {
    const int j = wave * 16 + jj;
    float w[8]; ldf(Wk + (size_t)(h*64 + j) * DD, lane, w);
    float sdot = w[0]*nl[0]+w[1]*nl[1]+w[2]*nl[2]+w[3]*nl[3]
               + w[4]*nl[4]+w[5]*nl[5]+w[6]*nl[6]+w[7]*nl[7];
    sdot = wred(sdot);
    if (lane == 0) ksl[j] = sdot * fac;
  }
  __syncthreads();

  float a0 = 0.f, a1 = 0.f;
  const float* base = Wq + (size_t)(h*64) * DD;
#pragma unroll 16
  for (int j = 0; j < 64; ++j) {
    const float kk = ksl[j];
    a0 += base[(size_t)j*DD + tid]       * kk;
    a1 += base[(size_t)j*DD + tid + 256] * kk;
  }

  // transform: mp = g*m; scalars c = sum be*m, sm = sum mp
  const float gq0 = g[tid], gq1 = g[tid + 256];
  const float bq0 = be[tid], bq1 = be[tid + 256];
  const float mp0 = a0 * gq0, mp1 = a1 * gq1;
  float* mo = mp + (((size_t)p*4 + b)*8 + h) * DD;
  mo[tid]       = mp0;
  mo[tid + 256] = mp1;

  float cp = a0*bq0 + a1*bq1;
  float sp = mp0 + mp1;
  cp = wred(cp); sp = wred(sp);
  if (lane == 0) { cs2[wave] = cp; ss2[wave] = sp; }
  __syncthreads();
  if (tid == 0) {
    const int idx = ((p*4 + b)*8 + h);
    cv[idx]  = cs2[0]+cs2[1]+cs2[2]+cs2[3];
    smv[idx] = ss2[0]+ss2[1]+ss2[2]+ss2[3];
  }
}

// ---------------------------------------------------------------------------
// K4: final gates + output. 4 rows per wave, 16 per block.
// Dots of raw v vs 16 mp vectors; 64-value halving-butterfly reduce
// (lane L ends with dot (r=L>>4, j=L&15)); MLP lane-parallel on lanes 0..7.
// Grid: 1024 blocks, 256 threads.
// ---------------------------------------------------------------------------
__global__ __launch_bounds__(256) void final_kernel(
    const float* __restrict__ xv_in, const float* __restrict__ xa_in,
    const float* __restrict__ mp, const float* __restrict__ cv,
    const float* __restrict__ smv, const float* __restrict__ fs,
    const float* __restrict__ vg_W1, const float* __restrict__ vg_b1,
    const float* __restrict__ vg_W2, const float* __restrict__ vg_b2,
    const float* __restrict__ ag_W1, const float* __restrict__ ag_b1,
    const float* __restrict__ ag_W2, const float* __restrict__ ag_b2,
    float* __restrict__ out_v, float* __restrict__ out_a)
{
  const int blk = blockIdx.x;
  const int s = blk >> 9, b = (blk >> 7) & 3, tile = blk & 127;
  const int tid = threadIdx.x, lane = tid & 63;
  const int wave = tid >> 6;
  const float* x = s ? xa_in : xv_in;
  float* out     = s ? out_a : out_v;
  const int row0 = b * TT + tile * 16 + wave * 4;

  // stage both layers' MLP params once
  __shared__ float mlp[2][161];
  {
    const float* W1p = s ? ag_W1 : vg_W1;   // (2,16,8)
    const float* b1p = s ? ag_b1 : vg_b1;   // (2,16)
    const float* W2p = s ? ag_W2 : vg_W2;   // (2,16)
    const float* b2p = s ? ag_b2 : vg_b2;   // (2)
    if (tid < 128)       { mlp[0][tid] = W1p[tid];       mlp[1][tid] = W1p[128 + tid]; }
    else if (tid < 144)  { mlp[0][tid] = b1p[tid - 128]; mlp[1][tid] = b1p[tid - 112]; }
    else if (tid < 160)  { mlp[0][tid] = W2p[tid - 144]; mlp[1][tid] = W2p[tid - 128]; }
    else if (tid == 160) { mlp[0][160] = b2p[0];         mlp[1][160] = b2p[1]; }
  }
  __syncthreads();

  const float flag = fs[(((s ? 0 : 1) * 4) + b) * 4 + 1];   // key-mask side

  // rows + stats (capture my job-row's stats via lane&3 == r)
  float v[4][8];
  float myMean = 0.f, myRstd = 1.f;
#pragma unroll
  for (int r = 0; r < 4; ++r) {
    ldf(x + (size_t)(row0 + r) * DD, lane, v[r]);
    float s1 = 0.f, s2 = 0.f;
#pragma unroll
    for (int k = 0; k < 8; ++k) { s1 += v[r][k]; s2 += v[r][k]*v[r][k]; }
    s1 = wred(s1); s2 = wred(s2);
    const float mean = s1 * (1.f / (float)DD);
    const float rstd = rsqrtf(s2 * (1.f / (float)DD) - mean*mean + EPS);
    if ((lane & 3) == r) { myMean = mean; myRstd = rstd; }
  }

  // 64 dot partials: a[r*16 + l*8 + h] = v[r] . mp[l,h] (this lane's 8 elems)
  float a[64];
  const float* mpb0 = mp + ((size_t)(s*4 + b) * 8) * DD;        // l=0 -> p=s
  const float* mpb1 = mp + ((size_t)((2+s)*4 + b) * 8) * DD;    // l=1 -> p=2+s
#pragma unroll
  for (int l = 0; l < 2; ++l) {
    const float* mb_ = l ? mpb1 : mpb0;
#pragma unroll
    for (int h = 0; h < HH; ++h) {
      float w[8]; ldf(mb_ + (size_t)h * DD, lane, w);
      const int j = l*8 + h;
#pragma unroll
      for (int r = 0; r < 4; ++r) {
        a[r*16 + j] = v[r][0]*w[0] + v[r][1]*w[1] + v[r][2]*w[2] + v[r][3]*w[3]
                    + v[r][4]*w[4] + v[r][5]*w[5] + v[r][6]*w[6] + v[r][7]*w[7];
      }
    }
  }

  // halving butterfly: 64 values x 64 lanes -> lane L holds full sum of a[L].
  // invariant before step k: a[m] = partial for idx (m<<k)|(lane&((1<<k)-1)),
  // summed over the lane's 2^k-group.
#pragma unroll
  for (int k = 0; k < 6; ++k) {
    const int bit = (lane >> k) & 1;
#pragma unroll
    for (int m = 0; m < (64 >> (k + 1)); ++m) {
      const float keep = bit ? a[2*m+1] : a[2*m];
      const float send = bit ? a[2*m]   : a[2*m+1];
      a[m] = keep + __shfl_xor(send, 1 << k);
    }
  }

  // gather: job lane jl in 0..7 -> (r = jl&3, l = jl>>2); needs dots at
  // lanes r*16 + l*8 + h. Executed by ALL lanes (shfl needs full wave).
  const int gr = lane & 3, gl = (lane >> 2) & 1;
  float q[8];
#pragma unroll
  for (int h = 0; h < HH; ++h) q[h] = __shfl(a[0], gr*16 + gl*8 + h);

  float gpart = 1.f;
  if (lane < 8) {
    const int l = lane >> 2;
    const int p = l*2 + s;
    const float* cb  = cv  + ((size_t)p*4 + b) * 8;
    const float* sbv = smv + ((size_t)p*4 + b) * 8;
    float rel[8];
#pragma unroll
    for (int h = 0; h < HH; ++h)
      rel[h] = myRstd * (q[h] - myMean * sbv[h]) + cb[h];
    float z = mlp[l][160];
#pragma unroll
    for (int e = 0; e < 16; ++e) {
      float h1 = mlp[l][128 + e];
#pragma unroll
      for (int h = 0; h < HH; ++h) h1 += rel[h] * mlp[l][e*8 + h];
      z += fmaxf(h1, 0.f) * mlp[l][144 + e];
    }
    gpart = 1.f + flag * (1.f / (1.f + expf(-z)));
  }

#pragma unroll
  for (int r = 0; r < 4; ++r) {
    const float sc = __shfl(gpart, r) * __shfl(gpart, 4 + r);
    float* orow = out + (size_t)(row0 + r) * DD;
    *reinterpret_cast<float4*>(orow + lane*4) =
        make_float4(v[r][0]*sc, v[r][1]*sc, v[r][2]*sc, v[r][3]*sc);
    *reinterpret_cast<float4*>(orow + 256 + lane*4) =
        make_float4(v[r][4]*sc, v[r][5]*sc, v[r][6]*sc, v[r][7]*sc);
  }
}

// ---------------------------------------------------------------------------
extern "C" void kernel_launch(void* const* d_in, const int* in_sizes, int n_in,
                              void* d_out, int out_size, void* d_ws, size_t ws_size,
                              hipStream_t stream) {
  const float* x_vid = (const float*)d_in[0];
  const float* x_aud = (const float*)d_in[1];
  const int* vid_kpm = (const int*)d_in[2];
  const int* aud_kpm = (const int*)d_in[3];
  const float* Wq_vid         = (const float*)d_in[4];
  const float* Wk_aud_for_vid = (const float*)d_in[5];
  const float* Wq_aud         = (const float*)d_in[6];
  const float* Wk_vid_for_aud = (const float*)d_in[7];
  const float* vg_W1 = (const float*)d_in[8];
  const float* vg_b1 = (const float*)d_in[9];
  const float* vg_W2 = (const float*)d_in[10];
  const float* vg_b2 = (const float*)d_in[11];
  const float* ag_W1 = (const float*)d_in[12];
  const float* ag_b1 = (const float*)d_in[13];
  const float* ag_W2 = (const float*)d_in[14];
  const float* ag_b2 = (const float*)d_in[15];
  const float* vid_ln_g = (const float*)d_in[16];
  const float* vid_ln_b = (const float*)d_in[17];
  const float* aud_ln_g = (const float*)d_in[18];
  const float* aud_ln_b = (const float*)d_in[19];

  const size_t BTD = (size_t)BB * TT * DD;
  float* out_v = (float*)d_out;
  float* out_a = out_v + BTD;

  float* partial = (float*)d_ws;                       // 2*4*64*512 = 1 MB
  float* S       = partial + (size_t)8 * 64 * DD;      // 2*4*512
  float* fs      = S + (size_t)8 * DD;                 // 8*4
  float* mpw     = fs + 32;                            // 4*4*8*512 = 256 KB
  float* cvw     = mpw + (size_t)4 * 4 * 8 * DD;       // 128
  float* smw     = cvw + 128;                          // 128

  sums_kernel<<<512, 256, 0, stream>>>(x_vid, x_aud, vid_kpm, aud_kpm, partial);
  reduce_kernel<<<256, 256, 0, stream>>>(partial, vid_kpm, aud_kpm, S, fs);
  mphase_kernel<<<128, 256, 0, stream>>>(
      S, fs, Wq_vid, Wk_aud_for_vid, Wq_aud, Wk_vid_for_aud,
      vid_ln_g, vid_ln_b, aud_ln_g, aud_ln_b, mpw, cvw, smw);
  final_kernel<<<1024, 256, 0, stream>>>(
      x_vid, x_aud, mpw, cvw, smw, fs,
      vg_W1, vg_b1, vg_W2, vg_b2, ag_W1, ag_b1, ag_W2, ag_b2,
      out_v, out_a);
}

// Round 9
// 49.224 us; speedup vs baseline: 25.3481x; 1.0341x over previous
//
#include <hip/hip_runtime.h>
#include <math.h>

// Problem constants (B,T,D,H,L from the reference)
#define BB 4
#define TT 2048
#define DD 512
#define HH 8
#define EPS 1e-5f
#define SCALE 0.125f            // dh^-0.5, dh=64
#define WW ((size_t)DD * DD)

// Algebra (verified R7/R8): phase updates are per-row scalings; LN is
// scale-invariant, so all 4 phases decouple. rel[h] is affine in raw v:
//   rel[h] = rstd*( v.(g*m) - mean*sum(g*m) ) + sum(be*m)
// Pipeline: sums (masked sum of normalized rows) -> mphase2 (S-reduce +
// mask stats + ks + m, pre-transformed) -> final (dots + gates + scale).

__device__ __forceinline__ float wred(float s) {
#pragma unroll
  for (int o = 32; o > 0; o >>= 1) s += __shfl_xor(s, o);
  return s;
}

__device__ __forceinline__ void ldf(const float* p, int lane, float f[8]) {
  float4 a = *reinterpret_cast<const float4*>(p + lane * 4);
  float4 c = *reinterpret_cast<const float4*>(p + 256 + lane * 4);
  f[0]=a.x; f[1]=a.y; f[2]=a.z; f[3]=a.w;
  f[4]=c.x; f[5]=c.y; f[6]=c.z; f[7]=c.w;
}

// ---------------------------------------------------------------------------
// K1: masked sum of normalized rows, both sides.
// Grid: 512 blocks, 256 threads; 32 rows/block. partial[(s*4+b)*64+tile][d]
// ---------------------------------------------------------------------------
__global__ __launch_bounds__(256) void sums_kernel(
    const float* __restrict__ xv, const float* __restrict__ xa,
    const int* __restrict__ vkpm, const int* __restrict__ akpm,
    float* __restrict__ partial)
{
  const int blk  = blockIdx.x;
  const int s    = blk >> 8;
  const int b    = (blk >> 6) & 3;
  const int tile = blk & 63;
  const int wave = threadIdx.x >> 6, lane = threadIdx.x & 63;
  const float* x  = s ? xa : xv;
  const int* kpm  = s ? akpm : vkpm;
  const int row0  = b * TT + tile * 32 + wave * 8;

  __shared__ float lds[4][DD];

  float acc[8] = {0.f,0.f,0.f,0.f,0.f,0.f,0.f,0.f};
  for (int r = 0; r < 8; ++r) {
    const int row = row0 + r;
    float v[8]; ldf(x + (size_t)row * DD, lane, v);
    float s1 = 0.f, s2 = 0.f;
#pragma unroll
    for (int k = 0; k < 8; ++k) { s1 += v[k]; s2 += v[k]*v[k]; }
    s1 = wred(s1); s2 = wred(s2);
    const float mean = s1 * (1.f / (float)DD);
    const float var  = s2 * (1.f / (float)DD) - mean * mean;
    const float rstd = rsqrtf(var + EPS);
    if (kpm[row] == 0) {          // wave-uniform
#pragma unroll
      for (int k = 0; k < 8; ++k) acc[k] += (v[k] - mean) * rstd;
    }
  }
#pragma unroll
  for (int k = 0; k < 4; ++k) {
    lds[wave][lane*4+k]       = acc[k];
    lds[wave][256+lane*4+k]   = acc[4+k];
  }
  __syncthreads();
  const int tid = threadIdx.x;
  float s0 = lds[0][tid] + lds[1][tid] + lds[2][tid] + lds[3][tid];
  float s1 = lds[0][tid+256] + lds[1][tid+256] + lds[2][tid+256] + lds[3][tid+256];
  float* p = partial + ((size_t)(s*4 + b) * 64 + tile) * DD;
  p[tid]       = s0;
  p[tid + 256] = s1;
}

// ---------------------------------------------------------------------------
// K2: per (p,b,h): inline S-reduce (16x redundant, L2), inline mask stats,
// ks[j] = fac*Wk[h*64+j,:].nsum, m -> emitted pre-transformed:
//   mp = g*m; sm = sum(mp); c = sum(be*m).  p in {0,1} h==0 blocks write fs.
// Grid: 4*4*8 = 128 blocks, 256 threads.
// ---------------------------------------------------------------------------
__global__ __launch_bounds__(256) void mphase2_kernel(
    const float* __restrict__ partial,
    const int* __restrict__ vkpm, const int* __restrict__ akpm,
    const float* __restrict__ Wq_v, const float* __restrict__ Wk_av,
    const float* __restrict__ Wq_a, const float* __restrict__ Wk_va,
    const float* __restrict__ vid_g, const float* __restrict__ vid_b,
    const float* __restrict__ aud_g, const float* __restrict__ aud_b,
    float* __restrict__ mp,         // (4,4,8,512)
    float* __restrict__ cv,         // (4,4,8)
    float* __restrict__ smv,        // (4,4,8)
    float* __restrict__ fs)         // (8,4): {fac, flag, cnt}
{
  const int blk = blockIdx.x;
  const int p = blk >> 5, b = (blk >> 3) & 3, h = blk & 7;
  const int layer = p >> 1;
  const int isA = ((p & 1) == 0);   // A phases: vid queries, aud keys
  const int tid = threadIdx.x, wave = tid >> 6, lane = tid & 63;

  __shared__ float4 red[256];
  __shared__ float nsum_s[DD];
  __shared__ float ksl[64];
  __shared__ float csh[4];
  __shared__ float cs2[4], ss2[4];

  const int ksb = (isA ? 1 : 0) * 4 + b;        // key side slot

  // inline S reduce over 64 tiles (t-split in halves, float4 per thread)
  {
    const int half = tid >> 7;                  // t in [0,32) or [32,64)
    const int i    = tid & 127;
    const float* pp = partial + ((size_t)ksb * 64 + half * 32) * DD + i * 4;
    float4 acc = make_float4(0.f, 0.f, 0.f, 0.f);
#pragma unroll 8
    for (int t = 0; t < 32; ++t) {
      float4 u = *reinterpret_cast<const float4*>(pp + (size_t)t * DD);
      acc.x += u.x; acc.y += u.y; acc.z += u.z; acc.w += u.w;
    }
    red[tid] = acc;
  }

  // inline mask count
  const int* mk = isA ? akpm : vkpm;
  {
    int cnt = 0;
#pragma unroll
    for (int q = 0; q < 8; ++q) cnt += (mk[b * TT + q * 256 + tid] == 0) ? 1 : 0;
    float fc = wred((float)cnt);
    if (lane == 0) csh[wave] = fc;
  }
  __syncthreads();
  if (tid < 128) {
    float4 a0 = red[tid], a1 = red[tid + 128];
    *reinterpret_cast<float4*>(&nsum_s[tid * 4]) =
        make_float4(a0.x + a1.x, a0.y + a1.y, a0.z + a1.z, a0.w + a1.w);
  }
  __syncthreads();

  const float vc   = csh[0] + csh[1] + csh[2] + csh[3];
  const float fac  = SCALE / fmaxf(vc, 1.f);
  const float cntf = vc;
  if (layer == 0 && h == 0 && tid == 0) {   // p=0 -> ksb=4+b, p=1 -> ksb=b
    fs[ksb * 4 + 0] = fac;
    fs[ksb * 4 + 1] = (vc > 0.f) ? 1.f : 0.f;
    fs[ksb * 4 + 2] = vc;
  }

  const float* g  = (isA ? vid_g : aud_g) + (size_t)layer * DD;
  const float* be = (isA ? vid_b : aud_b) + (size_t)layer * DD;
  const float* Wk = (isA ? Wk_av : Wk_va) + (size_t)layer * WW;
  const float* Wq = (isA ? Wq_v  : Wq_a ) + (size_t)layer * WW;

  float gv[8], bv[8], sv[8], nl[8];
  ldf(g, lane, gv); ldf(be, lane, bv);
  {
    float4 a = *reinterpret_cast<const float4*>(&nsum_s[lane * 4]);
    float4 c = *reinterpret_cast<const float4*>(&nsum_s[256 + lane * 4]);
    sv[0]=a.x; sv[1]=a.y; sv[2]=a.z; sv[3]=a.w;
    sv[4]=c.x; sv[5]=c.y; sv[6]=c.z; sv[7]=c.w;
  }
#pragma unroll
  for (int k = 0; k < 8; ++k) nl[k] = sv[k]*gv[k] + cntf*bv[k];

#pragma unroll 4
  for (int jj = 0; jj < 16; ++jj) {
    const int j = wave * 16 + jj;
    float w[8]; ldf(Wk + (size_t)(h*64 + j) * DD, lane, w);
    float sdot = w[0]*nl[0]+w[1]*nl[1]+w[2]*nl[2]+w[3]*nl[3]
               + w[4]*nl[4]+w[5]*nl[5]+w[6]*nl[6]+w[7]*nl[7];
    sdot = wred(sdot);
    if (lane == 0) ksl[j] = sdot * fac;
  }
  __syncthreads();

  float a0 = 0.f, a1 = 0.f;
  const float* base = Wq + (size_t)(h*64) * DD;
#pragma unroll 16
  for (int j = 0; j < 64; ++j) {
    const float kk = ksl[j];
    a0 += base[(size_t)j*DD + tid]       * kk;
    a1 += base[(size_t)j*DD + tid + 256] * kk;
  }

  // transform: mp = g*m; scalars c = sum be*m, sm = sum mp
  const float gq0 = g[tid], gq1 = g[tid + 256];
  const float bq0 = be[tid], bq1 = be[tid + 256];
  const float mp0 = a0 * gq0, mp1 = a1 * gq1;
  float* mo = mp + (((size_t)p*4 + b)*8 + h) * DD;
  mo[tid]       = mp0;
  mo[tid + 256] = mp1;

  float cp = a0*bq0 + a1*bq1;
  float sp = mp0 + mp1;
  cp = wred(cp); sp = wred(sp);
  if (lane == 0) { cs2[wave] = cp; ss2[wave] = sp; }
  __syncthreads();
  if (tid == 0) {
    const int idx = ((p*4 + b)*8 + h);
    cv[idx]  = cs2[0]+cs2[1]+cs2[2]+cs2[3];
    smv[idx] = ss2[0]+ss2[1]+ss2[2]+ss2[3];
  }
}

// ---------------------------------------------------------------------------
// K3: final gates + output. 2 rows per wave, 8 per block (high TLP).
// 32 dot partials -> 32-value halving butterfly (+1 xor32 finish);
// MLP lane-parallel on lanes 0..3 (4 jobs = 2 rows x 2 layers).
// Grid: 2*4*256 = 2048 blocks, 256 threads.
// ---------------------------------------------------------------------------
__global__ __launch_bounds__(256) void final_kernel(
    const float* __restrict__ xv_in, const float* __restrict__ xa_in,
    const float* __restrict__ mp, const float* __restrict__ cv,
    const float* __restrict__ smv, const float* __restrict__ fs,
    const float* __restrict__ vg_W1, const float* __restrict__ vg_b1,
    const float* __restrict__ vg_W2, const float* __restrict__ vg_b2,
    const float* __restrict__ ag_W1, const float* __restrict__ ag_b1,
    const float* __restrict__ ag_W2, const float* __restrict__ ag_b2,
    float* __restrict__ out_v, float* __restrict__ out_a)
{
  const int blk = blockIdx.x;
  const int s = blk >> 10, b = (blk >> 8) & 3, tile = blk & 255;
  const int tid = threadIdx.x, lane = tid & 63;
  const int wave = tid >> 6;
  const float* x = s ? xa_in : xv_in;
  float* out     = s ? out_a : out_v;
  const int row0 = b * TT + tile * 8 + wave * 2;

  // stage both layers' MLP params once
  __shared__ float mlp[2][161];
  {
    const float* W1p = s ? ag_W1 : vg_W1;   // (2,16,8)
    const float* b1p = s ? ag_b1 : vg_b1;   // (2,16)
    const float* W2p = s ? ag_W2 : vg_W2;   // (2,16)
    const float* b2p = s ? ag_b2 : vg_b2;   // (2)
    if (tid < 128)       { mlp[0][tid] = W1p[tid];       mlp[1][tid] = W1p[128 + tid]; }
    else if (tid < 144)  { mlp[0][tid] = b1p[tid - 128]; mlp[1][tid] = b1p[tid - 112]; }
    else if (tid < 160)  { mlp[0][tid] = W2p[tid - 144]; mlp[1][tid] = W2p[tid - 128]; }
    else if (tid == 160) { mlp[0][160] = b2p[0];         mlp[1][160] = b2p[1]; }
  }
  __syncthreads();

  const float flag = fs[(((s ? 0 : 1) * 4) + b) * 4 + 1];   // key-mask side

  // 2 rows + stats (capture my job-row's stats via lane&1 == r)
  float v[2][8];
  float myMean = 0.f, myRstd = 1.f;
#pragma unroll
  for (int r = 0; r < 2; ++r) {
    ldf(x + (size_t)(row0 + r) * DD, lane, v[r]);
    float s1 = 0.f, s2 = 0.f;
#pragma unroll
    for (int k = 0; k < 8; ++k) { s1 += v[r][k]; s2 += v[r][k]*v[r][k]; }
    s1 = wred(s1); s2 = wred(s2);
    const float mean = s1 * (1.f / (float)DD);
    const float rstd = rsqrtf(s2 * (1.f / (float)DD) - mean*mean + EPS);
    if ((lane & 1) == r) { myMean = mean; myRstd = rstd; }
  }

  // 32 dot partials: a[r*16 + l*8 + h] = v[r] . mp[l,h] (this lane's 8 elems)
  float a[32];
  const float* mpb0 = mp + ((size_t)(s*4 + b) * 8) * DD;        // l=0 -> p=s
  const float* mpb1 = mp + ((size_t)((2+s)*4 + b) * 8) * DD;    // l=1 -> p=2+s
#pragma unroll
  for (int l = 0; l < 2; ++l) {
    const float* mb_ = l ? mpb1 : mpb0;
#pragma unroll
    for (int h = 0; h < HH; ++h) {
      float w[8]; ldf(mb_ + (size_t)h * DD, lane, w);
      const int j = l*8 + h;
#pragma unroll
      for (int r = 0; r < 2; ++r) {
        a[r*16 + j] = v[r][0]*w[0] + v[r][1]*w[1] + v[r][2]*w[2] + v[r][3]*w[3]
                    + v[r][4]*w[4] + v[r][5]*w[5] + v[r][6]*w[6] + v[r][7]*w[7];
      }
    }
  }

  // halving butterfly over 32 values; lane L ends with full dot idx (L&31)
#pragma unroll
  for (int k = 0; k < 5; ++k) {
    const int bit = (lane >> k) & 1;
#pragma unroll
    for (int m = 0; m < (32 >> (k + 1)); ++m) {
      const float keep = bit ? a[2*m+1] : a[2*m];
      const float send = bit ? a[2*m]   : a[2*m+1];
      a[m] = keep + __shfl_xor(send, 1 << k);
    }
  }
  const float dotv = a[0] + __shfl_xor(a[0], 32);

  // gather: job lane jl in 0..3 -> (r = jl&1, l = jl>>1); dots at lanes
  // r*16 + l*8 + h. Executed by ALL lanes (shfl needs full wave).
  const int gr = lane & 1, gl = (lane >> 1) & 1;
  float q[8];
#pragma unroll
  for (int h = 0; h < HH; ++h) q[h] = __shfl(dotv, gr*16 + gl*8 + h);

  float gpart = 1.f;
  if (lane < 4) {
    const int l = lane >> 1;
    const int p = l*2 + s;
    const float* cb  = cv  + ((size_t)p*4 + b) * 8;
    const float* sbv = smv + ((size_t)p*4 + b) * 8;
    float rel[8];
#pragma unroll
    for (int h = 0; h < HH; ++h)
      rel[h] = myRstd * (q[h] - myMean * sbv[h]) + cb[h];
    float z = mlp[l][160];
#pragma unroll
    for (int e = 0; e < 16; ++e) {
      float h1 = mlp[l][128 + e];
#pragma unroll
      for (int h = 0; h < HH; ++h) h1 += rel[h] * mlp[l][e*8 + h];
      z += fmaxf(h1, 0.f) * mlp[l][144 + e];
    }
    gpart = 1.f + flag * (1.f / (1.f + expf(-z)));
  }

#pragma unroll
  for (int r = 0; r < 2; ++r) {
    const float sc = __shfl(gpart, r) * __shfl(gpart, 2 + r);
    float* orow = out + (size_t)(row0 + r) * DD;
    *reinterpret_cast<float4*>(orow + lane*4) =
        make_float4(v[r][0]*sc, v[r][1]*sc, v[r][2]*sc, v[r][3]*sc);
    *reinterpret_cast<float4*>(orow + 256 + lane*4) =
        make_float4(v[r][4]*sc, v[r][5]*sc, v[r][6]*sc, v[r][7]*sc);
  }
}

// ---------------------------------------------------------------------------
extern "C" void kernel_launch(void* const* d_in, const int* in_sizes, int n_in,
                              void* d_out, int out_size, void* d_ws, size_t ws_size,
                              hipStream_t stream) {
  const float* x_vid = (const float*)d_in[0];
  const float* x_aud = (const float*)d_in[1];
  const int* vid_kpm = (const int*)d_in[2];
  const int* aud_kpm = (const int*)d_in[3];
  const float* Wq_vid         = (const float*)d_in[4];
  const float* Wk_aud_for_vid = (const float*)d_in[5];
  const float* Wq_aud         = (const float*)d_in[6];
  const float* Wk_vid_for_aud = (const float*)d_in[7];
  const float* vg_W1 = (const float*)d_in[8];
  const float* vg_b1 = (const float*)d_in[9];
  const float* vg_W2 = (const float*)d_in[10];
  const float* vg_b2 = (const float*)d_in[11];
  const float* ag_W1 = (const float*)d_in[12];
  const float* ag_b1 = (const float*)d_in[13];
  const float* ag_W2 = (const float*)d_in[14];
  const float* ag_b2 = (const float*)d_in[15];
  const float* vid_ln_g = (const float*)d_in[16];
  const float* vid_ln_b = (const float*)d_in[17];
  const float* aud_ln_g = (const float*)d_in[18];
  const float* aud_ln_b = (const float*)d_in[19];

  const size_t BTD = (size_t)BB * TT * DD;
  float* out_v = (float*)d_out;
  float* out_a = out_v + BTD;

  float* partial = (float*)d_ws;                       // 2*4*64*512 = 1 MB
  float* fs      = partial + (size_t)8 * 64 * DD;      // 8*4
  float* mpw     = fs + 32;                            // 4*4*8*512 = 256 KB
  float* cvw     = mpw + (size_t)4 * 4 * 8 * DD;       // 128
  float* smw     = cvw + 128;                          // 128

  sums_kernel<<<512, 256, 0, stream>>>(x_vid, x_aud, vid_kpm, aud_kpm, partial);
  mphase2_kernel<<<128, 256, 0, stream>>>(
      partial, vid_kpm, aud_kpm,
      Wq_vid, Wk_aud_for_vid, Wq_aud, Wk_vid_for_aud,
      vid_ln_g, vid_ln_b, aud_ln_g, aud_ln_b, mpw, cvw, smw, fs);
  final_kernel<<<2048, 256, 0, stream>>>(
      x_vid, x_aud, mpw, cvw, smw, fs,
      vg_W1, vg_b1, vg_W2, vg_b2, ag_W1, ag_b1, ag_W2, ag_b2,
      out_v, out_a);
}